// Round 9
// baseline (120.793 us; speedup 1.0000x reference)
//
#include <hip/hip_runtime.h>

// WisePooling: per-segment column mean + EPS.
// x: (N, D=512) fp32; graph: (S, 2) int32 [start, end] inclusive, starts/ends sorted.
// out[s] = mean(x[start_s..end_s], axis=0) + EPS.
//
// Ownership decomposition, SINGLE kernel: tile k (128 rows) owns the segments
// whose START lies in [r0, r1]. It streams rows from its first owned start to
// its last owned end (possibly past the tile edge). Segments tile the row
// space, so every row is read exactly once globally and every segment has
// exactly one writer: plain nontemporal stores, no atomics, no zero pass, no
// init kernel. The block-uniform binary search (first start >= r0) runs in the
// prologue and overlaps across the 2048 co-resident blocks. Descriptors stage
// into LDS (commit path is lgkmcnt-only; vmcnt queue stays pure row data);
// rows stream with 8-deep rotated nontemporal prefetch (clamped addresses).
// Duplicate-cut chains ([c,c] overlapping the next start) are handled by the
// commit-while with acc re-seeded from the current row; a cross-tile duplicate
// may be committed by both writers with bit-identical values (benign).

#define EPS_VAL 0.006f
#define DIM 512
#define DV 128     // float4 per row
#define TILE 128   // rows per block (N % TILE == 0 here)
#define GROUP 8
#define MAXSEG 64  // LDS descriptor window; P(Poisson(4) > 64) ~ 0

typedef float f32x4 __attribute__((ext_vector_type(4)));

__global__ __launch_bounds__(128, 4) void pool_own_kernel(
    const float* __restrict__ x,
    const int* __restrict__ graph,
    float* __restrict__ out,
    int N, int S) {
  __shared__ int2 sdesc[MAXSEG];
  const int r0 = blockIdx.x * TILE;
  const int r1 = r0 + TILE - 1;
  const int t = threadIdx.x;  // 0..127: one float4 column slice

  // First segment with start >= r0 (starts sorted). Block-uniform search.
  int lo = 0, hi = S;
  while (lo < hi) {
    int mid = (lo + hi) >> 1;
    if (graph[2 * mid] < r0) lo = mid + 1; else hi = mid;
  }

  if (t < MAXSEG) {
    const int si = lo + t;
    sdesc[t] = (si < S) ? reinterpret_cast<const int2*>(graph)[si]
                        : make_int2(N + TILE, N + TILE);  // start > any r1
  }
  __syncthreads();

  // Count owned segments (start <= r1); uniform LDS scan (expected ~4 iters).
  int nown = 0;
  while (nown < MAXSEG && sdesc[nown].x <= r1) ++nown;
  if (nown == 0) return;  // a long segment spans this whole tile; owner reads it

  const int rs = sdesc[0].x;           // first row we read
  const int re = sdesc[nown - 1].y;    // last row we read (inclusive)
  const int nm1 = N - 1;

  const f32x4* x4 = reinterpret_cast<const f32x4*>(x);

  int s = 0;  // owned-segment cursor (sdesc-relative)
  int seg_st = sdesc[0].x;
  int seg_en = sdesc[0].y;

  f32x4 acc = (f32x4){0.f, 0.f, 0.f, 0.f};
  f32x4 buf[GROUP];

  // Nontemporal row load, clamped in-bounds (rows past re are unused).
#define LDROW(row) \
  __builtin_nontemporal_load(x4 + (size_t)((row) < nm1 ? (row) : nm1) * DV + t)

#define COMMIT(rr, v)                                                         \
  while ((rr) == seg_en) {                                                    \
    const float inv = 1.0f / (float)(seg_en - seg_st + 1);                    \
    f32x4 res = acc * inv + EPS_VAL;                                          \
    __builtin_nontemporal_store(                                              \
        res, reinterpret_cast<f32x4*>(out + (size_t)(lo + s) * DIM) + t);     \
    ++s;                                                                      \
    int2 nx;                                                                  \
    if (s < MAXSEG) nx = sdesc[s]; /* lgkmcnt only */                         \
    else nx = (lo + s < S) ? reinterpret_cast<const int2*>(graph)[lo + s]     \
                           : make_int2(N + TILE, N + TILE);                   \
    seg_st = nx.x; seg_en = nx.y;                                             \
    if (seg_st <= (rr)) acc = (v);                                            \
    else acc = (f32x4){0.f, 0.f, 0.f, 0.f};                                   \
  }

  int r = rs;
#pragma unroll
  for (int j = 0; j < GROUP; ++j) buf[j] = LDROW(r + j);

  // Main loop: full groups of 8 rows, 8-deep rotated prefetch.
  while (r + GROUP <= re + 1) {
    f32x4 nbuf[GROUP];
#pragma unroll
    for (int j = 0; j < GROUP; ++j) nbuf[j] = LDROW(r + GROUP + j);
#pragma unroll
    for (int j = 0; j < GROUP; ++j) {
      const int rr = r + j;
      const f32x4 v = buf[j];
      acc += v;
      COMMIT(rr, v)
    }
#pragma unroll
    for (int j = 0; j < GROUP; ++j) buf[j] = nbuf[j];
    r += GROUP;
  }

  // Tail: rows r..re already resident in buf[0..re-r].
#pragma unroll
  for (int j = 0; j < GROUP; ++j) {
    const int rr = r + j;
    if (rr <= re) {
      const f32x4 v = buf[j];
      acc += v;
      COMMIT(rr, v)
    }
  }
#undef LDROW
#undef COMMIT
}

extern "C" void kernel_launch(void* const* d_in, const int* in_sizes, int n_in,
                              void* d_out, int out_size, void* d_ws, size_t ws_size,
                              hipStream_t stream) {
  const float* x = (const float*)d_in[0];
  const int* graph = (const int*)d_in[1];
  float* out = (float*)d_out;

  const int N = in_sizes[0] / DIM;
  const int S = in_sizes[1] / 2;
  const int ntiles = N / TILE;  // 2048 blocks = 8/CU co-resident

  pool_own_kernel<<<ntiles, 128, 0, stream>>>(x, graph, out, N, S);
}

// Round 10
// 105.178 us; speedup vs baseline: 1.1485x; 1.1485x over previous
//
#include <hip/hip_runtime.h>

// WisePooling: per-segment column mean + EPS.
// x: (N, D=512) fp32; graph: (S, 2) int32 [start, end] inclusive, starts/ends sorted.
// out[s] = mean(x[start_s..end_s], axis=0) + EPS.
//
// One block per 128-row tile; 128 threads = one float4 column slice each.
// 2048 blocks = 8 per CU co-resident (16 waves/CU). init_kernel computes
// per-tile first-overlapping-segment lo[] and zeros ONLY tile-crossing
// segments (~4 MB instead of the full 16.8 MB output). pool_tile_kernel
// stages the tile's segment descriptors into LDS (commit path is
// lgkmcnt-only; the vmcnt queue stays pure row data), then streams 128 rows
// with 8-deep rotated nontemporal prefetch, fully unrolled. Fully-inside
// segments commit with nontemporal stores; the ~2K boundary-crossing
// segments combine via fp32 atomics on their pre-zeroed rows. The tile
// owning seg.start adds EPS exactly once.
//
// (Round 9's single-kernel ownership variant regressed 105->121 us: clamped
// per-row addressing + runtime trip counts broke the pure constant-stride
// stream. This is the round-8 design, the measured optimum.)

#define EPS_VAL 0.006f
#define DIM 512
#define DV 128     // float4 per row
#define TILE 128   // rows per block (N % TILE == 0 here)
#define GROUP 8
#define NGROUPS (TILE / GROUP)  // 16, fully unrolled
#define MAXSEG 64  // LDS descriptor window; P(Poisson(4) > 64) ~ 0

typedef float f32x4 __attribute__((ext_vector_type(4)));

__global__ __launch_bounds__(256) void init_kernel(
    const int* __restrict__ graph,
    f32x4* __restrict__ out4,
    int* __restrict__ lo_arr,
    int ntiles, int S, int N) {
  const int i = blockIdx.x * 256 + threadIdx.x;
  // Per-tile binary search: first segment with end >= tile start.
  if (i < ntiles) {
    const int r0 = i * TILE;
    int lo = 0, hi = S - 1;
    while (lo < hi) {
      int mid = (lo + hi) >> 1;
      if (graph[2 * mid + 1] < r0) lo = mid + 1; else hi = mid;
    }
    lo_arr[i] = lo;
  }
  // Zero only boundary-crossing segments: one (segment, slice) per thread.
  if (i < S * 128) {
    const int s = i >> 7;
    const int t = i & 127;
    const int st = graph[2 * s];
    const int en = graph[2 * s + 1];
    if (st / TILE != en / TILE) {
      out4[(size_t)s * DV + t] = (f32x4){0.f, 0.f, 0.f, 0.f};
    }
  }
}

__global__ __launch_bounds__(128, 4) void pool_tile_kernel(
    const float* __restrict__ x,
    const int* __restrict__ graph,
    const int* __restrict__ lo_arr,
    float* __restrict__ out,
    int N, int S) {
  __shared__ int2 sdesc[MAXSEG];
  const int r0 = blockIdx.x * TILE;
  const int r1 = r0 + TILE - 1;
  const int t = threadIdx.x;  // 0..127

  const int lo = lo_arr[blockIdx.x];
  if (t < MAXSEG) {
    const int si = lo + t;
    sdesc[t] = (si < S) ? reinterpret_cast<const int2*>(graph)[si]
                        : make_int2(N, N);
  }
  __syncthreads();

  int s = lo;
  int seg_st = sdesc[0].x;
  int seg_en = sdesc[0].y;

  const f32x4* xp = reinterpret_cast<const f32x4*>(x) + (size_t)r0 * DV + t;

  f32x4 acc = (f32x4){0.f, 0.f, 0.f, 0.f};
  f32x4 buf[GROUP];
#pragma unroll
  for (int j = 0; j < GROUP; ++j) buf[j] = __builtin_nontemporal_load(xp + j * DV);
  xp += GROUP * DV;

#pragma unroll
  for (int g = 0; g < NGROUPS; ++g) {
    f32x4 nbuf[GROUP];
    if (g + 1 < NGROUPS) {
#pragma unroll
      for (int j = 0; j < GROUP; ++j) nbuf[j] = __builtin_nontemporal_load(xp + j * DV);
      xp += GROUP * DV;
    }
#pragma unroll
    for (int j = 0; j < GROUP; ++j) {
      const int r = r0 + g * GROUP + j;
      const f32x4 v = buf[j];
      acc += v;
      // Wave-uniform commit branch (r, seg_en are block-uniform).
      while (r == seg_en) {
        const float inv = 1.0f / (float)(seg_en - seg_st + 1);
        f32x4 res = acc * inv;
        float* op = out + (size_t)s * DIM + t * 4;
        if (seg_st >= r0) {
          // Fully inside this tile: sole contributor + EPS owner.
          res += EPS_VAL;
          __builtin_nontemporal_store(res, reinterpret_cast<f32x4*>(op));
        } else {
          unsafeAtomicAdd(op + 0, res.x);
          unsafeAtomicAdd(op + 1, res.y);
          unsafeAtomicAdd(op + 2, res.z);
          unsafeAtomicAdd(op + 3, res.w);
        }
        ++s;
        const int widx = s - lo;
        int2 nx;
        if (widx < MAXSEG) {
          nx = sdesc[widx];  // LDS: lgkmcnt only, vmcnt queue undisturbed
        } else {
          nx = (s < S) ? reinterpret_cast<const int2*>(graph)[s]
                       : make_int2(N, N);  // cold fallback, ~never taken
        }
        seg_st = nx.x; seg_en = nx.y;
        // Overlapping start (degenerate duplicate chain): re-seed with row r.
        if (seg_st <= r) { acc = v; }
        else { acc = (f32x4){0.f, 0.f, 0.f, 0.f}; }
      }
    }
#pragma unroll
    for (int j = 0; j < GROUP; ++j) buf[j] = nbuf[j];
  }

  // Tail: current segment extends past the tile -> atomic partial.
  if (s < S && seg_st <= r1) {
    const float inv = 1.0f / (float)(seg_en - seg_st + 1);
    f32x4 res = acc * inv;
    if (seg_st >= r0) {  // EPS owner
      res += EPS_VAL;
    }
    float* op = out + (size_t)s * DIM + t * 4;
    unsafeAtomicAdd(op + 0, res.x);
    unsafeAtomicAdd(op + 1, res.y);
    unsafeAtomicAdd(op + 2, res.z);
    unsafeAtomicAdd(op + 3, res.w);
  }
}

extern "C" void kernel_launch(void* const* d_in, const int* in_sizes, int n_in,
                              void* d_out, int out_size, void* d_ws, size_t ws_size,
                              hipStream_t stream) {
  const float* x = (const float*)d_in[0];
  const int* graph = (const int*)d_in[1];
  float* out = (float*)d_out;
  int* lo_arr = (int*)d_ws;  // ntiles ints

  const int N = in_sizes[0] / DIM;
  const int S = in_sizes[1] / 2;
  const int ntiles = N / TILE;

  const int init_items = (S * 128 > ntiles) ? S * 128 : ntiles;
  init_kernel<<<(init_items + 255) / 256, 256, 0, stream>>>(
      graph, reinterpret_cast<f32x4*>(out), lo_arr, ntiles, S, N);

  pool_tile_kernel<<<ntiles, 128, 0, stream>>>(x, graph, lo_arr, out, N, S);
}